// Round 1
// baseline (15522.337 us; speedup 1.0000x reference)
//
#include <hip/hip_runtime.h>
#include <hip/hip_bf16.h>

// Problem: B=64, T=512, D=1024, H=1024, 2-layer masked LSTM (Keras semantics).
// Persistent kernel: 256 WGs x 256 thr, one WG per CU, manual grid barrier.
// Layer-pipelined: super-step s runs layer0@t=s and layer1@t=s-1 (513 barriers).
// Each WG owns 8 h-cols of one layer; its [W;U] slice (2048x32 bf16) lives in LDS.

#define NB 64
#define NTT 512
#define ND 1024
#define NH 1024

typedef __attribute__((ext_vector_type(8))) short short8;
typedef __attribute__((ext_vector_type(4))) float floatx4;
typedef __attribute__((ext_vector_type(4))) unsigned short ushort4v;

#define BS_PITCH 2056                         // 2048 + 8 bf16 pad (16B-aligned rows, 2-way banks = free)
#define LDS_RED_OFF (32 * BS_PITCH * 2)       // 131584
#define LDS_LEN_OFF (LDS_RED_OFF + 12 * 2 * 64 * 16) // +24576 = 156160
#define LDS_TOTAL   (LDS_LEN_OFF + 256)       // 156416 <= 163840

__device__ __forceinline__ unsigned short f2bf(float f) {
  unsigned int u = __float_as_uint(f);
  u += 0x7fffu + ((u >> 16) & 1u);            // round-to-nearest-even
  return (unsigned short)(u >> 16);
}
__device__ __forceinline__ float sigmf(float x) { return 1.0f / (1.0f + __expf(-x)); }
__device__ __forceinline__ float tanhfa(float x) { return 1.0f - 2.0f / (1.0f + __expf(2.0f * x)); }

// Two-level grid barrier: 8 leaf counters (128B apart) + root. Monotonic, no reset.
__device__ __forceinline__ void gridbar(unsigned long long* bar, unsigned long long iter) {
  __syncthreads();
  if (threadIdx.x == 0) {
    __threadfence();  // release: flush this XCD's L2 so h-writes reach coherence point
    unsigned long long* leaf = bar + 16ull * (1ull + (unsigned long long)(blockIdx.x & 7));
    unsigned long long old = __hip_atomic_fetch_add(leaf, 1ull, __ATOMIC_RELAXED, __HIP_MEMORY_SCOPE_AGENT);
    if (old == iter * 32ull - 1ull)  // last of this leaf's 32 WGs for this iteration
      __hip_atomic_fetch_add(bar, 1ull, __ATOMIC_RELAXED, __HIP_MEMORY_SCOPE_AGENT);
    while (__hip_atomic_load(bar, __ATOMIC_RELAXED, __HIP_MEMORY_SCOPE_AGENT) < iter * 8ull)
      __builtin_amdgcn_s_sleep(1);
    __threadfence();  // acquire: invalidate stale L1/L2 before reading h
  }
  __syncthreads();
}

__global__ __launch_bounds__(256, 1) void lstm2_persist(
    const float* __restrict__ xin, const int* __restrict__ lens,
    const float* __restrict__ W0, const float* __restrict__ U0, const float* __restrict__ b0v,
    const float* __restrict__ W1, const float* __restrict__ U1, const float* __restrict__ b1v,
    float* __restrict__ out, unsigned long long* __restrict__ bar,
    unsigned short* __restrict__ hbufs) {
  extern __shared__ char smem[];
  unsigned short* Bs = (unsigned short*)smem;          // [32][BS_PITCH] bf16 weight slice
  float* red = (float*)(smem + LDS_RED_OFF);           // [12 slots][2 nt][64 lane][4] f32
  int* lensL = (int*)(smem + LDS_LEN_OFF);

  const int tid = threadIdx.x;
  const int wg = blockIdx.x;
  const int layer = wg >> 7;          // WGs 0..127 -> layer0, 128..255 -> layer1
  const int hc0 = (wg & 127) * 8;     // this WG's 8 h-columns
  const int wave = tid >> 6;          // K-quarter owner
  const int lane = tid & 63;
  const int c16 = lane & 15;          // MFMA row (A) / col (B,D) index
  const int rowgrp = lane >> 4;
  const int koff8 = rowgrp * 8;

  unsigned short* h0b0 = hbufs;                 // h0 double buffer, [64][1024] bf16 each
  unsigned short* h0b1 = hbufs + 65536;
  unsigned short* h1b0 = hbufs + 131072;
  unsigned short* h1b1 = hbufs + 196608;

  // ---------------- phase 0 ----------------
  const unsigned int gid = (unsigned int)wg * 256u + (unsigned int)tid;
  // zero all four h buffers (4*64*1024 bf16 = 131072 dwords)
  for (unsigned int i = gid; i < 131072u; i += 65536u) ((unsigned int*)hbufs)[i] = 0u;
  // x (B,T,D) fp32 -> bf16, aliased into d_out: xb[t][b][0:1024] at byte (b*512+t)*4096.
  // xb[t] is dead after super-step t; rnnout[:,t] (same chunk) is written at t+1.
  {
    const floatx4* xs = (const floatx4*)xin;
    for (unsigned int q = gid; q < 8388608u; q += 65536u) {
      unsigned int d4 = q & 255u;
      unsigned int bt = q >> 8;  // b*512 + t
      floatx4 v = xs[q];
      ushort4v o;
      o.x = f2bf(v.x); o.y = f2bf(v.y); o.z = f2bf(v.z); o.w = f2bf(v.w);
      *((ushort4v*)((char*)out + (size_t)bt * 4096) + d4) = o;
    }
  }
  // [W;U] slice -> LDS, Bs[n][k]: n = gate*8 + j (32 z-cols), k = 0..2047
  {
    const float* Wm = layer ? W1 : W0;
    const float* Um = layer ? U1 : U0;
    for (int idx = tid; idx < 65536; idx += 256) {
      int n = idx & 31, k = idx >> 5;
      int zc = (n >> 3) * 1024 + hc0 + (n & 7);
      float v = (k < 1024) ? Wm[(size_t)k * 4096 + zc] : Um[(size_t)(k - 1024) * 4096 + zc];
      Bs[n * BS_PITCH + k] = f2bf(v);
    }
  }
  if (tid < 64) lensL[tid] = lens[tid];
  const float* bv = layer ? b1v : b0v;
  const float bias0 = bv[((c16 >> 3)) * 1024 + hc0 + (c16 & 7)];       // n = c16      (gates i,f)
  const float bias1 = bv[(2 + (c16 >> 3)) * 1024 + hc0 + (c16 & 7)];   // n = 16 + c16 (gates g,o)

  gridbar(bar, 1ull);

  // ---------------- recurrence ----------------
  float hst[4] = {0.f, 0.f, 0.f, 0.f};
  float cst[4] = {0.f, 0.f, 0.f, 0.f};

  const unsigned short* bRow0 = Bs + (size_t)c16 * BS_PITCH + wave * 512 + koff8;
  const unsigned short* bRow1 = Bs + (size_t)(16 + c16) * BS_PITCH + wave * 512 + koff8;

#pragma unroll 1
  for (int s = 0; s <= NTT; ++s) {
    const int t = layer ? (s - 1) : s;
    const bool active = layer ? (s >= 1) : (s < NTT);
    if (active) {
      // A source for this wave's K-quarter. k<1024: layer input; k>=1024: recurrent h.
      const char* base0;
      size_t pitch;
      if (layer == 0) {
        if (wave < 2) {  // x_t, aliased in d_out, row pitch 512*4096 B
          base0 = (const char*)out + (size_t)t * 4096 + (size_t)wave * 1024;
          pitch = (size_t)NTT * 4096;
        } else {         // h0_{t-1} = h0b[(t+1)&1]
          base0 = (const char*)((s & 1) ? h0b0 : h0b1) + (size_t)(wave - 2) * 1024;
          pitch = 2048;
        }
      } else {
        if (wave < 2) {  // out0[t] = h0b[t&1]
          base0 = (const char*)((t & 1) ? h0b1 : h0b0) + (size_t)wave * 1024;
        } else {         // h1_{t-1} = h1b[(t+1)&1]
          base0 = (const char*)((t & 1) ? h1b0 : h1b1) + (size_t)(wave - 2) * 1024;
        }
        pitch = 2048;
      }
      const char* aP = base0 + (size_t)c16 * pitch + (size_t)koff8 * 2;

      floatx4 acc[4][2];
#pragma unroll
      for (int mt = 0; mt < 4; ++mt)
#pragma unroll
        for (int nt = 0; nt < 2; ++nt) {
          floatx4 z = {0.f, 0.f, 0.f, 0.f};
          acc[mt][nt] = z;
        }

      // 16 k-tiles of 32; 4-slot register pipeline, prefetch distance 3.
      short8 apf[4][4];
      short8 bpf[4][2];
#pragma unroll
      for (int kt = 0; kt < 19; ++kt) {
        if (kt < 16) {
          const int sl = kt & 3;
          const size_t off = (size_t)kt * 64;
          apf[sl][0] = *(const short8*)(aP + off);
          apf[sl][1] = *(const short8*)(aP + 16 * pitch + off);
          apf[sl][2] = *(const short8*)(aP + 32 * pitch + off);
          apf[sl][3] = *(const short8*)(aP + 48 * pitch + off);
          bpf[sl][0] = *(const short8*)(bRow0 + kt * 32);
          bpf[sl][1] = *(const short8*)(bRow1 + kt * 32);
        }
        if (kt >= 3) {
          const int sl = (kt - 3) & 3;
#pragma unroll
          for (int mt = 0; mt < 4; ++mt)
#pragma unroll
            for (int nt = 0; nt < 2; ++nt)
              acc[mt][nt] = __builtin_amdgcn_mfma_f32_16x16x32_bf16(
                  apf[sl][mt], bpf[sl][nt], acc[mt][nt], 0, 0, 0);
        }
      }

      // cross-wave K reduction: wave w keeps m-tile w, ships the other 3 via LDS
#pragma unroll
      for (int mt = 0; mt < 4; ++mt)
        if (mt != wave) {
          int slot = mt * 3 + wave - (wave > mt ? 1 : 0);
          *(floatx4*)&red[((slot * 2 + 0) * 64 + lane) * 4] = acc[mt][0];
          *(floatx4*)&red[((slot * 2 + 1) * 64 + lane) * 4] = acc[mt][1];
        }
      __syncthreads();
      floatx4 z0 = acc[wave][0], z1 = acc[wave][1];
#pragma unroll
      for (int q = 0; q < 3; ++q) {
        int slot = wave * 3 + q;
        z0 += *(const floatx4*)&red[((slot * 2 + 0) * 64 + lane) * 4];
        z1 += *(const floatx4*)&red[((slot * 2 + 1) * 64 + lane) * 4];
      }
      z0 += bias0;
      z1 += bias1;

      unsigned short* hW = layer ? ((t & 1) ? h1b1 : h1b0) : ((s & 1) ? h0b1 : h0b0);

#pragma unroll
      for (int r = 0; r < 4; ++r) {
        float zi = z0[r], zg = z1[r];
        float zf = __shfl_xor(zi, 8);  // f-gate lives in lane c16^8
        float zo = __shfl_xor(zg, 8);  // o-gate lives in lane c16^8
        if (c16 < 8) {
          int b = wave * 16 + rowgrp * 4 + r;
          float ig = sigmf(zi), fg = sigmf(zf), gg = tanhfa(zg), og = sigmf(zo);
          float cn = fg * cst[r] + ig * gg;
          float hn = og * tanhfa(cn);
          bool m = t < lensL[b];
          float h2 = m ? hn : hst[r];
          float c2 = m ? cn : cst[r];
          hst[r] = h2;
          cst[r] = c2;
          int col = hc0 + c16;
          hW[b * 1024 + col] = f2bf(h2);
          if (layer) out[((size_t)b * 512 + (size_t)t) * 1024 + col] = h2;  // rnnout
        }
      }
    }
    gridbar(bar, (unsigned long long)(s + 2));
  }

  // final h, c (layer-1 register state)
  if (layer && c16 < 8) {
#pragma unroll
    for (int r = 0; r < 4; ++r) {
      int b = wave * 16 + rowgrp * 4 + r;
      int col = hc0 + c16;
      out[(size_t)33554432 + (size_t)b * 1024 + col] = hst[r];
      out[(size_t)33554432 + 65536 + (size_t)b * 1024 + col] = cst[r];
    }
  }
}

extern "C" void kernel_launch(void* const* d_in, const int* in_sizes, int n_in,
                              void* d_out, int out_size, void* d_ws, size_t ws_size,
                              hipStream_t stream) {
  (void)in_sizes; (void)n_in; (void)out_size; (void)ws_size;
  const float* x  = (const float*)d_in[0];
  const int* lens = (const int*)d_in[1];
  const float* W0 = (const float*)d_in[2];
  const float* U0 = (const float*)d_in[3];
  const float* b0 = (const float*)d_in[4];
  const float* W1 = (const float*)d_in[5];
  const float* U1 = (const float*)d_in[6];
  const float* b1 = (const float*)d_in[7];

  // opt in to >64KB dynamic LDS (idempotent; ignore error)
  (void)hipFuncSetAttribute((const void*)lstm2_persist,
                            hipFuncAttributeMaxDynamicSharedMemorySize, LDS_TOTAL);
  // zero barrier counters (root + 8 leaves) in ws
  hipMemsetAsync(d_ws, 0, 4096, stream);

  unsigned long long* bar = (unsigned long long*)d_ws;
  unsigned short* hbufs = (unsigned short*)((char*)d_ws + 4096);

  lstm2_persist<<<dim3(256), dim3(256), LDS_TOTAL, stream>>>(
      x, lens, W0, U0, b0, W1, U1, b1, (float*)d_out, bar, hbufs);
}

// Round 2
// 11763.886 us; speedup vs baseline: 1.3195x; 1.3195x over previous
//
#include <hip/hip_runtime.h>
#include <hip/hip_bf16.h>

// B=64, T=512, D=H=1024, 2-layer masked LSTM. Persistent kernel, 256 WGs x 256 thr.
// Layer-pipelined: super-step s = layer0@t=s + layer1@t=s-1. 513 grid barriers.
// v2: weights live in VGPRs (128/wave, fragment order); A-frags loaded directly
// global->VGPR with 8-deep ring (32 outstanding 16B loads/wave); leaf/captain
// barrier with read-only broadcast lines. LDS only holds the 24KB K-reduction.

#define NTT 512

typedef __attribute__((ext_vector_type(8))) short short8;
typedef __attribute__((ext_vector_type(4))) float floatx4;
typedef __attribute__((ext_vector_type(4))) unsigned short ushort4v;
typedef unsigned long long ull;

#define LDS_TOTAL 90112  // force 1 WG/CU (160KB pool); first 24KB = reduction buf

__device__ __forceinline__ unsigned short f2bf(float f) {
  unsigned int u = __float_as_uint(f);
  u += 0x7fffu + ((u >> 16) & 1u);  // RNE
  return (unsigned short)(u >> 16);
}
__device__ __forceinline__ float sigmf(float x) { return 1.0f / (1.0f + __expf(-x)); }
__device__ __forceinline__ float tanhfa(float x) { return 1.0f - 2.0f / (1.0f + __expf(2.0f * x)); }

// Barrier v3: 8 arrival leaves -> 8 captains -> root (8 RMWs) -> 8 bcast lines.
// Non-captains only ever READ their bcast line; root is polled by 8 WGs only.
__device__ __forceinline__ void gridbar(ull* bar, ull iter, int bid) {
  __syncthreads();
  if (threadIdx.x == 0) {
    const int leaf = bid & 7;
    ull* la = bar + 16 + 16 * leaf;    // arrival counter, 32 WGs RMW
    ull* bc = bar + 144 + 16 * leaf;   // broadcast epoch, captain-write, 31 read
    __builtin_amdgcn_fence(__ATOMIC_RELEASE, "agent");
    __hip_atomic_fetch_add(la, 1ull, __ATOMIC_RELAXED, __HIP_MEMORY_SCOPE_AGENT);
    if (bid < 8) {  // captain of leaf==bid
      while (__hip_atomic_load(la, __ATOMIC_RELAXED, __HIP_MEMORY_SCOPE_AGENT) < iter * 32ull)
        __builtin_amdgcn_s_sleep(1);
      __hip_atomic_fetch_add(bar, 1ull, __ATOMIC_RELAXED, __HIP_MEMORY_SCOPE_AGENT);
      while (__hip_atomic_load(bar, __ATOMIC_RELAXED, __HIP_MEMORY_SCOPE_AGENT) < iter * 8ull)
        __builtin_amdgcn_s_sleep(1);
      __hip_atomic_store(bc, iter, __ATOMIC_RELAXED, __HIP_MEMORY_SCOPE_AGENT);
    } else {
      while (__hip_atomic_load(bc, __ATOMIC_RELAXED, __HIP_MEMORY_SCOPE_AGENT) < iter)
        __builtin_amdgcn_s_sleep(1);
    }
    __builtin_amdgcn_fence(__ATOMIC_ACQUIRE, "agent");
  }
  __syncthreads();
}

__global__ __launch_bounds__(256, 1) void lstm2_persist(
    const float* __restrict__ xin, const int* __restrict__ lens,
    const float* __restrict__ W0, const float* __restrict__ U0, const float* __restrict__ b0v,
    const float* __restrict__ W1, const float* __restrict__ U1, const float* __restrict__ b1v,
    float* __restrict__ out, ull* __restrict__ bar,
    unsigned short* __restrict__ hbufs) {
  extern __shared__ char smem[];
  float* red = (float*)smem;  // [12 slots][2 nt][64 lane][4] f32 = 24KB

  const int tid = threadIdx.x;
  const int bid = blockIdx.x;
  const int layer = bid >> 7;          // 0..127 -> layer0, 128..255 -> layer1
  const int hc0 = (bid & 127) * 8;     // 8 owned h-cols
  const int wave = tid >> 6;           // K-quarter owner (512 k each)
  const int lane = tid & 63;
  const int c16 = lane & 15;
  const int rowgrp = lane >> 4;

  unsigned short* h0b0 = hbufs;
  unsigned short* h0b1 = hbufs + 65536;
  unsigned short* h1b0 = hbufs + 131072;
  unsigned short* h1b1 = hbufs + 196608;

  // ---------------- phase 0 ----------------
  const unsigned int gid = (unsigned int)bid * 256u + (unsigned int)tid;
  for (unsigned int i = gid; i < 131072u; i += 65536u) ((unsigned int*)hbufs)[i] = 0u;
  {
    // x (B,T,D) fp32 -> bf16 aliased into d_out at (b*512+t)*4096 bytes.
    // xb[t] read by layer0 at super-step t; rnnout[:,t] (same bytes) written at t+1.
    const floatx4* xs = (const floatx4*)xin;
    for (unsigned int q = gid; q < 8388608u; q += 65536u) {
      unsigned int d4 = q & 255u;
      unsigned int bt = q >> 8;
      floatx4 v = xs[q];
      ushort4v o;
      o.x = f2bf(v.x); o.y = f2bf(v.y); o.z = f2bf(v.z); o.w = f2bf(v.w);
      *((ushort4v*)((char*)out + (size_t)bt * 4096) + d4) = o;
    }
  }

  // B fragments -> VGPRs, fragment order. Wave w holds K in [512w,512w+512):
  // waves 0,1 = input-projection rows (W), waves 2,3 = recurrent rows (U).
  // frag(kt,nt): lane holds B[k=kt*32+rowgrp*8+j][n=nt*16+c16] (j=0..7).
  const float* Wm = layer ? W1 : W0;
  const float* Um = layer ? U1 : U0;
  const float* Bsrc = (wave < 2) ? Wm : Um;
  const int kbase = (wave & 1) * 512;
  short8 bf[16][2];
#pragma unroll
  for (int kt = 0; kt < 16; ++kt)
#pragma unroll
    for (int nt = 0; nt < 2; ++nt) {
      const int zc = (nt * 2 + (c16 >> 3)) * 1024 + hc0 + (c16 & 7);
      const float* col = Bsrc + (size_t)(kbase + kt * 32 + rowgrp * 8) * 4096 + zc;
      short8 v;
#pragma unroll
      for (int j = 0; j < 8; ++j) v[j] = (short)f2bf(col[(size_t)j * 4096]);
      bf[kt][nt] = v;
    }

  const float* bv = layer ? b1v : b0v;
  const float bias0 = bv[(c16 >> 3) * 1024 + hc0 + (c16 & 7)];        // gates i,f
  const float bias1 = bv[(2 + (c16 >> 3)) * 1024 + hc0 + (c16 & 7)];  // gates g,o
  int lens4[4];
#pragma unroll
  for (int r = 0; r < 4; ++r) lens4[r] = lens[wave * 16 + rowgrp * 4 + r];

  gridbar(bar, 1ull, bid);

  // ---------------- recurrence ----------------
  float hst[4] = {0.f, 0.f, 0.f, 0.f};
  float cst[4] = {0.f, 0.f, 0.f, 0.f};

#pragma unroll 1
  for (int s = 0; s <= NTT; ++s) {
    const int t = layer ? (s - 1) : s;
    const bool active = layer ? (s >= 1) : (s < NTT);
    if (active) {
      // A base for this wave's K-range. Per-lane frag addr:
      //   base + (mt*16+c16)*pitch + (kt*32 + rowgrp*8)*2
      const char* base0;
      size_t pitch;
      if (layer == 0) {
        if (wave < 2) { base0 = (const char*)out + (size_t)t * 4096 + (size_t)wave * 1024;
                        pitch = (size_t)NTT * 4096; }
        else          { base0 = (const char*)((s & 1) ? h0b0 : h0b1) + (size_t)(wave - 2) * 1024;
                        pitch = 2048; }
      } else {
        if (wave < 2) { base0 = (const char*)((t & 1) ? h0b1 : h0b0) + (size_t)wave * 1024; }
        else          { base0 = (const char*)((t & 1) ? h1b0 : h1b1) + (size_t)(wave - 2) * 1024; }
        pitch = 2048;
      }
      const char* aP = base0 + (size_t)c16 * pitch + (size_t)rowgrp * 16;
      const char* aPm[4];
#pragma unroll
      for (int mt = 0; mt < 4; ++mt) aPm[mt] = aP + (size_t)mt * 16 * pitch;

      floatx4 acc[4][2];
#pragma unroll
      for (int mt = 0; mt < 4; ++mt)
#pragma unroll
        for (int nt = 0; nt < 2; ++nt) { floatx4 z = {0.f, 0.f, 0.f, 0.f}; acc[mt][nt] = z; }

      // A-frag ring, depth 8 (32 outstanding dwordx4 per wave).
      short8 af[8][4];
#pragma unroll
      for (int kt = 0; kt < 8; ++kt)
#pragma unroll
        for (int mt = 0; mt < 4; ++mt)
          af[kt][mt] = *(const short8*)(aPm[mt] + kt * 64);

#pragma unroll
      for (int kt = 0; kt < 16; ++kt) {
#pragma unroll
        for (int mt = 0; mt < 4; ++mt)
#pragma unroll
          for (int nt = 0; nt < 2; ++nt)
            acc[mt][nt] = __builtin_amdgcn_mfma_f32_16x16x32_bf16(
                af[kt & 7][mt], bf[kt][nt], acc[mt][nt], 0, 0, 0);
        if (kt < 8) {
#pragma unroll
          for (int mt = 0; mt < 4; ++mt)
            af[kt & 7][mt] = *(const short8*)(aPm[mt] + (kt + 8) * 64);
        }
      }

      // cross-wave K reduction (wave keeps m-tile == wave)
#pragma unroll
      for (int mt = 0; mt < 4; ++mt)
        if (mt != wave) {
          int slot = mt * 3 + wave - (wave > mt ? 1 : 0);
          *(floatx4*)&red[((slot * 2 + 0) * 64 + lane) * 4] = acc[mt][0];
          *(floatx4*)&red[((slot * 2 + 1) * 64 + lane) * 4] = acc[mt][1];
        }
      __syncthreads();
      floatx4 z0 = acc[wave][0], z1 = acc[wave][1];
#pragma unroll
      for (int q = 0; q < 3; ++q) {
        int slot = wave * 3 + q;
        z0 += *(const floatx4*)&red[((slot * 2 + 0) * 64 + lane) * 4];
        z1 += *(const floatx4*)&red[((slot * 2 + 1) * 64 + lane) * 4];
      }
      z0 += bias0;
      z1 += bias1;

      unsigned short* hW = layer ? ((t & 1) ? h1b1 : h1b0) : ((s & 1) ? h0b1 : h0b0);

#pragma unroll
      for (int r = 0; r < 4; ++r) {
        float zi = z0[r], zg = z1[r];
        float zf = __shfl_xor(zi, 8);
        float zo = __shfl_xor(zg, 8);
        if (c16 < 8) {
          int b = wave * 16 + rowgrp * 4 + r;
          float ig = sigmf(zi), fg = sigmf(zf), gg = tanhfa(zg), og = sigmf(zo);
          float cn = fg * cst[r] + ig * gg;
          float hn = og * tanhfa(cn);
          bool m = t < lens4[r];
          float h2 = m ? hn : hst[r];
          float c2 = m ? cn : cst[r];
          hst[r] = h2;
          cst[r] = c2;
          int col = hc0 + c16;
          hW[b * 1024 + col] = f2bf(h2);
          if (layer) out[((size_t)b * 512 + (size_t)t) * 1024 + col] = h2;
        }
      }
    }
    gridbar(bar, (ull)(s + 2), bid);
  }

  if (layer && c16 < 8) {
#pragma unroll
    for (int r = 0; r < 4; ++r) {
      int b = wave * 16 + rowgrp * 4 + r;
      int col = hc0 + c16;
      out[(size_t)33554432 + (size_t)b * 1024 + col] = hst[r];
      out[(size_t)33554432 + 65536 + (size_t)b * 1024 + col] = cst[r];
    }
  }
}

extern "C" void kernel_launch(void* const* d_in, const int* in_sizes, int n_in,
                              void* d_out, int out_size, void* d_ws, size_t ws_size,
                              hipStream_t stream) {
  (void)in_sizes; (void)n_in; (void)out_size; (void)ws_size;
  const float* x  = (const float*)d_in[0];
  const int* lens = (const int*)d_in[1];
  const float* W0 = (const float*)d_in[2];
  const float* U0 = (const float*)d_in[3];
  const float* b0 = (const float*)d_in[4];
  const float* W1 = (const float*)d_in[5];
  const float* U1 = (const float*)d_in[6];
  const float* b1 = (const float*)d_in[7];

  (void)hipFuncSetAttribute((const void*)lstm2_persist,
                            hipFuncAttributeMaxDynamicSharedMemorySize, LDS_TOTAL);
  hipMemsetAsync(d_ws, 0, 4096, stream);

  ull* bar = (ull*)d_ws;
  unsigned short* hbufs = (unsigned short*)((char*)d_ws + 4096);

  lstm2_persist<<<dim3(256), dim3(256), LDS_TOTAL, stream>>>(
      x, lens, W0, U0, b0, W1, U1, b1, (float*)d_out, bar, hbufs);
}

// Round 3
// 10552.902 us; speedup vs baseline: 1.4709x; 1.1148x over previous
//
#include <hip/hip_runtime.h>
#include <hip/hip_bf16.h>

// B=64, T=512, D=H=1024, 2-layer masked LSTM. Persistent kernel, 256 WGs x 256 thr.
// v3: NO per-step cache fences. h state flows through agent-scope (sc0/sc1,
// L2-bypassing) atomic loads/stores; x + weights stay L2/VGPR-resident.
// Per-layer 128-WG epoch barriers; layer0 free-runs up to 3 steps ahead
// (h0 ring of 4); layer1 waits on epoch0 >= t+1. x-frags prefetch pre-barrier.

#define NTT 512

typedef __attribute__((ext_vector_type(8))) short short8;
typedef __attribute__((ext_vector_type(4))) float floatx4;
typedef __attribute__((ext_vector_type(4))) unsigned short ushort4v;
typedef unsigned long long ull;

#define LDS_TOTAL 90112  // force 1 WG/CU; first 24KB = reduction buf

#define AT_LD(p) __hip_atomic_load((p), __ATOMIC_RELAXED, __HIP_MEMORY_SCOPE_AGENT)
#define AT_ST(p, v) __hip_atomic_store((p), (v), __ATOMIC_RELAXED, __HIP_MEMORY_SCOPE_AGENT)
#define AT_ADD(p, v) __hip_atomic_fetch_add((p), (v), __ATOMIC_RELAXED, __HIP_MEMORY_SCOPE_AGENT)

__device__ __forceinline__ unsigned short f2bf(float f) {
  unsigned int u = __float_as_uint(f);
  u += 0x7fffu + ((u >> 16) & 1u);  // RNE
  return (unsigned short)(u >> 16);
}
__device__ __forceinline__ float sigmf(float x) { return 1.0f / (1.0f + __expf(-x)); }
__device__ __forceinline__ float tanhfa(float x) { return 1.0f - 2.0f / (1.0f + __expf(2.0f * x)); }

// ---- phase-0 full-grid barrier (256 WGs), WITH full fences (publishes xb, hbuf zeros)
__device__ __forceinline__ void fullbar(ull* base, int bid) {
  __syncthreads();
  if (threadIdx.x == 0) {
    const int l = bid & 7;
    ull* la = base + 16 + 16 * l;
    ull* bc = base + 144 + 16 * l;
    __builtin_amdgcn_fence(__ATOMIC_RELEASE, "agent");
    AT_ADD(la, 1ull);
    if (bid < 8) {
      while (AT_LD(la) < 32ull) __builtin_amdgcn_s_sleep(1);
      AT_ADD(base, 1ull);
      while (AT_LD(base) < 8ull) __builtin_amdgcn_s_sleep(1);
      AT_ST(bc, 1ull);
    } else {
      while (AT_LD(bc) < 1ull) __builtin_amdgcn_s_sleep(1);
    }
    __builtin_amdgcn_fence(__ATOMIC_ACQUIRE, "agent");
  }
  __syncthreads();
}

// ---- per-layer epoch barrier: arrive (after own h-stores drained) ----
__device__ __forceinline__ void layer_arrive(ull* base, int sub, ull t1) {
  asm volatile("s_waitcnt vmcnt(0)" ::: "memory");  // per-wave: h sc1-stores acked at L3
  __syncthreads();
  if (threadIdx.x == 0) {
    const int l = sub & 7;
    ull* la = base + 16 + 16 * l;
    AT_ADD(la, 1ull);
    if (sub < 8) {  // captain of leaf==sub: aggregate 16 arrivals -> root -> bcast
      while (AT_LD(la) < t1 * 16ull) __builtin_amdgcn_s_sleep(1);
      AT_ADD(base, 1ull);
      while (AT_LD(base) < t1 * 8ull) __builtin_amdgcn_s_sleep(1);
      AT_ST(base + 144 + 16 * sub, t1);
    }
  }
}

// ---- wait for own-layer epoch >= ot and other-layer epoch >= xt (skip if <=0)
__device__ __forceinline__ void wait2(ull* own, long long ot, ull* oth, long long xt, int sub) {
  if (threadIdx.x == 0) {
    const int l = sub & 7;
    if (ot > 0)
      while (AT_LD(own + 144 + 16 * l) < (ull)ot) __builtin_amdgcn_s_sleep(1);
    if (xt > 0)
      while (AT_LD(oth + 144 + 16 * l) < (ull)xt) __builtin_amdgcn_s_sleep(1);
  }
  __syncthreads();
}

// ---- A-fragment load: COH = agent-coherent (L2-bypass) path for h buffers
template <bool COH>
__device__ __forceinline__ short8 ldfrag(const char* p) {
  if constexpr (COH) {
    union { short8 s; ull q[2]; } u;
    u.q[0] = AT_LD((const ull*)p);
    u.q[1] = AT_LD((const ull*)(p + 8));
    return u.s;
  } else {
    return *(const short8*)p;
  }
}

template <bool COH>
__device__ __forceinline__ void ringfill(const char* const* aPm, short8 (*af)[4]) {
#pragma unroll
  for (int kt = 0; kt < 8; ++kt)
#pragma unroll
    for (int mt = 0; mt < 4; ++mt) af[kt][mt] = ldfrag<COH>(aPm[mt] + kt * 64);
}

template <bool COH>
__device__ __forceinline__ void kmain(const char* const* aPm, short8 (*af)[4],
                                      const short8 (*bfr)[2], floatx4 (*acc)[2]) {
#pragma unroll
  for (int kt = 0; kt < 16; ++kt) {
#pragma unroll
    for (int mt = 0; mt < 4; ++mt)
#pragma unroll
      for (int nt = 0; nt < 2; ++nt)
        acc[mt][nt] = __builtin_amdgcn_mfma_f32_16x16x32_bf16(
            af[kt & 7][mt], bfr[kt][nt], acc[mt][nt], 0, 0, 0);
    if (kt < 8) {
#pragma unroll
      for (int mt = 0; mt < 4; ++mt)
        af[kt & 7][mt] = ldfrag<COH>(aPm[mt] + (kt + 8) * 64);
    }
  }
}

__global__ __launch_bounds__(256, 1) void lstm2_persist(
    const float* __restrict__ xin, const int* __restrict__ lens,
    const float* __restrict__ W0, const float* __restrict__ U0, const float* __restrict__ b0v,
    const float* __restrict__ W1, const float* __restrict__ U1, const float* __restrict__ b1v,
    float* __restrict__ out, ull* __restrict__ ws) {
  extern __shared__ char smem[];
  float* red = (float*)smem;  // [12][2][64][4] f32 = 24KB

  ull* bar0 = ws;           // layer-0 epoch tree: root@0, leaves@16+16l, bcast@144+16l
  ull* bar1 = ws + 512;     // layer-1 epoch tree
  ull* fbar = ws + 1024;    // phase-0 full barrier
  unsigned short* hbufs = (unsigned short*)(ws + 2048);  // byte 16384

  const int tid = threadIdx.x;
  const int bid = blockIdx.x;
  const int layer = bid >> 7;
  const int sub = bid & 127;
  const int hc0 = sub * 8;
  const int wave = tid >> 6;
  const int lane = tid & 63;
  const int c16 = lane & 15;
  const int rowgrp = lane >> 4;

  // h0 ring of 4 (layer0 may run ahead), h1 ping-pong of 2. 64x1024 bf16 each.
  unsigned short* h0r[4] = {hbufs, hbufs + 65536, hbufs + 131072, hbufs + 196608};
  unsigned short* h1r[2] = {hbufs + 262144, hbufs + 327680};

  // ---------------- phase 0 ----------------
  const unsigned int gid = (unsigned int)bid * 256u + (unsigned int)tid;
  for (unsigned int i = gid; i < 196608u; i += 65536u) ((unsigned int*)hbufs)[i] = 0u;
  {
    // x (B,T,D) fp32 -> bf16 aliased into d_out at (b*512+t)*4096 bytes.
    const floatx4* xs = (const floatx4*)xin;
    for (unsigned int q = gid; q < 8388608u; q += 65536u) {
      unsigned int d4 = q & 255u;
      unsigned int bt = q >> 8;
      floatx4 v = xs[q];
      ushort4v o;
      o.x = f2bf(v.x); o.y = f2bf(v.y); o.z = f2bf(v.z); o.w = f2bf(v.w);
      *((ushort4v*)((char*)out + (size_t)bt * 4096) + d4) = o;
    }
  }
  // B fragments -> VGPRs (wave w: K in [512w,512w+512); w<2 = W rows, w>=2 = U rows)
  const float* Wm = layer ? W1 : W0;
  const float* Um = layer ? U1 : U0;
  const float* Bsrc = (wave < 2) ? Wm : Um;
  const int kbase = (wave & 1) * 512;
  short8 bf[16][2];
#pragma unroll
  for (int kt = 0; kt < 16; ++kt)
#pragma unroll
    for (int nt = 0; nt < 2; ++nt) {
      const int zc = (nt * 2 + (c16 >> 3)) * 1024 + hc0 + (c16 & 7);
      const float* col = Bsrc + (size_t)(kbase + kt * 32 + rowgrp * 8) * 4096 + zc;
      short8 v;
#pragma unroll
      for (int j = 0; j < 8; ++j) v[j] = (short)f2bf(col[(size_t)j * 4096]);
      bf[kt][nt] = v;
    }
  const float* bv = layer ? b1v : b0v;
  const float bias0 = bv[(c16 >> 3) * 1024 + hc0 + (c16 & 7)];
  const float bias1 = bv[(2 + (c16 >> 3)) * 1024 + hc0 + (c16 & 7)];
  int lens4[4];
#pragma unroll
  for (int r = 0; r < 4; ++r) lens4[r] = lens[wave * 16 + rowgrp * 4 + r];

  fullbar(fbar, bid);

  // ---------------- recurrence ----------------
  float hst[4] = {0.f, 0.f, 0.f, 0.f};
  float cst[4] = {0.f, 0.f, 0.f, 0.f};
  const int col = hc0 + c16;

#pragma unroll 1
  for (int t = 0; t < NTT; ++t) {
    const char* aPm[4];
    short8 af[8][4];
    bool isX;  // this wave's A comes from x (normal loads) vs h (coherent loads)
    {
      const char* base0;
      size_t pitch;
      if (layer == 0) {
        if (wave < 2) { base0 = (const char*)out + (size_t)t * 4096 + (size_t)wave * 1024;
                        pitch = (size_t)NTT * 4096; isX = true; }
        else          { base0 = (const char*)h0r[(t + 3) & 3] + (size_t)(wave - 2) * 1024;
                        pitch = 2048; isX = false; }
      } else {
        if (wave < 2) { base0 = (const char*)h0r[t & 3] + (size_t)wave * 1024; }
        else          { base0 = (const char*)h1r[(t + 1) & 1] + (size_t)(wave - 2) * 1024; }
        pitch = 2048; isX = false;
      }
      const char* aP = base0 + (size_t)c16 * pitch + (size_t)rowgrp * 16;
#pragma unroll
      for (int mt = 0; mt < 4; ++mt) aPm[mt] = aP + (size_t)mt * 16 * pitch;
    }

    if (isX) ringfill<false>(aPm, af);  // x is static: prefetch before the wait

    if (layer == 0) wait2(bar0, t, bar1, (long long)t - 3, sub);
    else            wait2(bar1, t, bar0, (long long)t + 1, sub);

    floatx4 acc[4][2];
#pragma unroll
    for (int mt = 0; mt < 4; ++mt)
#pragma unroll
      for (int nt = 0; nt < 2; ++nt) { floatx4 z = {0.f, 0.f, 0.f, 0.f}; acc[mt][nt] = z; }

    if (isX) {
      kmain<false>(aPm, af, bf, acc);
    } else {
      ringfill<true>(aPm, af);
      kmain<true>(aPm, af, bf, acc);
    }

    // cross-wave K reduction (wave keeps m-tile == wave)
#pragma unroll
    for (int mt = 0; mt < 4; ++mt)
      if (mt != wave) {
        int slot = mt * 3 + wave - (wave > mt ? 1 : 0);
        *(floatx4*)&red[((slot * 2 + 0) * 64 + lane) * 4] = acc[mt][0];
        *(floatx4*)&red[((slot * 2 + 1) * 64 + lane) * 4] = acc[mt][1];
      }
    __syncthreads();
    floatx4 z0 = acc[wave][0], z1 = acc[wave][1];
#pragma unroll
    for (int q = 0; q < 3; ++q) {
      int slot = wave * 3 + q;
      z0 += *(const floatx4*)&red[((slot * 2 + 0) * 64 + lane) * 4];
      z1 += *(const floatx4*)&red[((slot * 2 + 1) * 64 + lane) * 4];
    }
    z0 += bias0;
    z1 += bias1;

    unsigned short* hW = layer ? h1r[t & 1] : h0r[t & 3];

#pragma unroll
    for (int r = 0; r < 4; ++r) {
      float zi = z0[r], zg = z1[r];
      float zf = __shfl_xor(zi, 8);
      float zo = __shfl_xor(zg, 8);
      float h2, hu_f = 0.f;
      unsigned short hu = 0;
      if (c16 < 8) {
        float ig = sigmf(zi), fg = sigmf(zf), gg = tanhfa(zg), og = sigmf(zo);
        float cn = fg * cst[r] + ig * gg;
        float hn = og * tanhfa(cn);
        bool m = t < lens4[r];
        h2 = m ? hn : hst[r];
        float c2 = m ? cn : cst[r];
        hst[r] = h2;
        cst[r] = c2;
        hu = f2bf(h2);
        hu_f = h2;
      }
      // pair adjacent cols -> one u32 coherent store (and float2 rnnout store)
      unsigned int up = __shfl_xor((unsigned int)hu, 1);
      float hp = __shfl_xor(hu_f, 1);
      if (c16 < 8 && !(c16 & 1)) {
        int b = wave * 16 + rowgrp * 4 + r;
        unsigned int w = (unsigned int)hu | (up << 16);
        AT_ST((unsigned int*)(hW + b * 1024 + col), w);
        if (layer) {
          float2 f2 = make_float2(hu_f, hp);
          *(float2*)&out[((size_t)b * 512 + (size_t)t) * 1024 + col] = f2;
        }
      }
    }

    if (layer == 0) layer_arrive(bar0, sub, (ull)(t + 1));
    else            layer_arrive(bar1, sub, (ull)(t + 1));
  }

  if (layer && c16 < 8) {
#pragma unroll
    for (int r = 0; r < 4; ++r) {
      int b = wave * 16 + rowgrp * 4 + r;
      out[(size_t)33554432 + (size_t)b * 1024 + col] = hst[r];
      out[(size_t)33554432 + 65536 + (size_t)b * 1024 + col] = cst[r];
    }
  }
}

extern "C" void kernel_launch(void* const* d_in, const int* in_sizes, int n_in,
                              void* d_out, int out_size, void* d_ws, size_t ws_size,
                              hipStream_t stream) {
  (void)in_sizes; (void)n_in; (void)out_size; (void)ws_size;
  const float* x  = (const float*)d_in[0];
  const int* lens = (const int*)d_in[1];
  const float* W0 = (const float*)d_in[2];
  const float* U0 = (const float*)d_in[3];
  const float* b0 = (const float*)d_in[4];
  const float* W1 = (const float*)d_in[5];
  const float* U1 = (const float*)d_in[6];
  const float* b1 = (const float*)d_in[7];

  (void)hipFuncSetAttribute((const void*)lstm2_persist,
                            hipFuncAttributeMaxDynamicSharedMemorySize, LDS_TOTAL);
  hipMemsetAsync(d_ws, 0, 16384, stream);  // bar0/bar1/fullbar

  lstm2_persist<<<dim3(256), dim3(256), LDS_TOTAL, stream>>>(
      x, lens, W0, U0, b0, W1, U1, b1, (float*)d_out, (ull*)d_ws);
}